// Round 7
// baseline (1367.173 us; speedup 1.0000x reference)
//
#include <hip/hip_runtime.h>

// HMM forward (CgpHmmCell): B=512, T=4096, S=64, M=125.
// Round 7: R6 MFMA scan + occupancy/conflict fixes.
//  - NCHUNK=128 (chunk 32 steps = 4 packs), BURN=16 (2 packs): 4096 waves =
//    4 waves/SIMD (R6 had 1/SIMD: all step latency exposed). +9% steps, 4x TLP.
//  - WPB=8 (512-thr blocks, grid 512 = 2 blocks/CU, LDS 54.7 KB/block).
//  - wsc stride 17->20: transpose write banks (8g+s) / read banks (16g+s)
//    are exactly <=2-way (free). R6's stride-17 was 4-way.
//  - truncation-only bf16 pack (uniform part of the bias is a surrogate
//    rescale -> cancels exactly in the mass identity).
// Algorithm: per wave 16 chunk-streams; alphaT is the MFMA B operand; A^T as
// 8 constant bf16 A-frags; lane owns one stream (C-layout col); per-step
// C->B transpose via per-wave LDS scratch; per-pack surrogate rescale;
// chunk contribution = S1-S0 mass identity (scales cancel); atomicAdd.

#define BATCH 512
#define T 4096
#define S 64
#define M 125
#define CHUNKP 4   // packs per chunk (32 steps)
#define BURNP 2    // burn packs (16 steps)
#define NPACK (CHUNKP + BURNP)
#define WPB 8
#define BSTR 68    // BmL row stride (floats)
#define WSTR 20    // transpose scratch row stride (u32): <=2-way banks

typedef __attribute__((ext_vector_type(8))) short bf16x8;
typedef __attribute__((ext_vector_type(4))) float f32x4;

union BFU { unsigned u[4]; bf16x8 v; };

__device__ __forceinline__ unsigned pk_trunc(float a, float b) {
    return (__float_as_uint(b) & 0xFFFF0000u) | (__float_as_uint(a) >> 16);
}
__device__ __forceinline__ unsigned pk_rne(float a, float b) {
    unsigned ua = __float_as_uint(a); ua += 0x7FFFu + ((ua >> 16) & 1u);
    unsigned ub = __float_as_uint(b); ub += 0x7FFFu + ((ub >> 16) & 1u);
    return (ub & 0xFFFF0000u) | (ua >> 16);
}

// ---------------- Phase 1: one-hot -> byte index (HBM-floor) ----------------
__global__ __launch_bounds__(256) void extract_obs(const float4* __restrict__ x4,
                                                   unsigned char* __restrict__ obs) {
    const long long n4 = (long long)BATCH * T * M / 4;
    long long stride = (long long)gridDim.x * blockDim.x;
    for (long long i = (long long)blockIdx.x * blockDim.x + threadIdx.x; i < n4; i += stride) {
        float4 v = x4[i];
        if (v.x != 0.0f || v.y != 0.0f || v.z != 0.0f || v.w != 0.0f) {
            long long e = i * 4;
            if (v.x != 0.0f) { long long r = (e + 0) / M; obs[r] = (unsigned char)(e + 0 - r * M); }
            if (v.y != 0.0f) { long long r = (e + 1) / M; obs[r] = (unsigned char)(e + 1 - r * M); }
            if (v.z != 0.0f) { long long r = (e + 2) / M; obs[r] = (unsigned char)(e + 2 - r * M); }
            if (v.w != 0.0f) { long long r = (e + 3) / M; obs[r] = (unsigned char)(e + 3 - r * M); }
        }
    }
}

// ---------------- Phase 2: MFMA scan, 16 streams per wave ----------------
__global__ __launch_bounds__(512, 4) void hmm_mfma(const unsigned char* __restrict__ obs,
                                                   const float* __restrict__ Iv,
                                                   const float* __restrict__ A,
                                                   const float* __restrict__ Bm,
                                                   float* __restrict__ out) {
    __shared__ __align__(16) float BmL[M * BSTR];     // 34000 B
    __shared__ __align__(16) float ILds[S];
    __shared__ unsigned wscAll[WPB][32 * WSTR];       // 20480 B

    const int tid = threadIdx.x, wv = tid >> 6, lane = tid & 63;
    const int s = lane & 15, g = lane >> 4;

    for (int i = tid; i < M * S; i += WPB * 64) BmL[(i >> 6) * BSTR + (i & 63)] = Bm[i];
    if (tid < S) ILds[tid] = Iv[tid];
    __syncthreads();

    // Constant A^T fragments: Aop[m][k] = A[k][m]; lane (s,g): m=16mt+s, k=32kf+8g+j.
    BFU Af[4][2];
#pragma unroll
    for (int mt = 0; mt < 4; ++mt)
#pragma unroll
        for (int kf = 0; kf < 2; ++kf)
#pragma unroll
            for (int j2 = 0; j2 < 4; ++j2) {
                int k0 = kf * 32 + g * 8 + 2 * j2;
                Af[mt][kf].u[j2] = pk_rne(A[(size_t)k0 * S + mt * 16 + s],
                                          A[(size_t)(k0 + 1) * S + mt * 16 + s]);
            }

    const int W = blockIdx.x * WPB + wv;   // 0..4095
    const int seq = W >> 3, hw = W & 7;
    const int chunk = hw * 16 + s;         // 0..127: this lane's stream
    const bool c0wave = (hw == 0);
    const bool is_c0 = c0wave && (s == 0);

    const unsigned long long* orow = (const unsigned long long*)(obs + (size_t)seq * T);
    const int idx0 = chunk * CHUNKP - BURNP;

    unsigned* wsc = wscAll[wv];

    BFU Bf[2];                             // alphaT fragments, init 1.0 (burn seed)
#pragma unroll
    for (int kf = 0; kf < 2; ++kf)
#pragma unroll
        for (int j = 0; j < 4; ++j) Bf[kf].u[j] = 0x3F803F80u;

    float w[4][4];
    float Ls = 0.f, S0v = 0.f, c = 1.f;

    int i0 = idx0 < 0 ? 0 : idx0;
    unsigned long long u = orow[i0];

    for (int p = 0; p < NPACK; ++p) {
        int in_ = idx0 + p + 1;
        in_ = in_ < 0 ? 0 : (in_ > T / 8 - 1 ? T / 8 - 1 : in_);
        unsigned long long un = orow[in_];          // prefetch next pack
        const bool ovp = c0wave && (p == BURNP);    // chunk-0 exact-init pack
#pragma unroll
        for (int k = 0; k < 8; ++k) {
            const int o = (int)((u >> (8 * k)) & 255ull);
            f32x4 E[4];
#pragma unroll
            for (int mt = 0; mt < 4; ++mt)
                E[mt] = *(const f32x4*)&BmL[o * BSTR + mt * 16 + g * 4];
            f32x4 acc[4];
#pragma unroll
            for (int mt = 0; mt < 4; ++mt) {
                f32x4 z = {0.f, 0.f, 0.f, 0.f};
                z = __builtin_amdgcn_mfma_f32_16x16x32_bf16(Af[mt][0].v, Bf[0].v, z, 0, 0, 0);
                acc[mt] = __builtin_amdgcn_mfma_f32_16x16x32_bf16(Af[mt][1].v, Bf[1].v, z, 0, 0, 0);
            }
#pragma unroll
            for (int mt = 0; mt < 4; ++mt)
#pragma unroll
                for (int r = 0; r < 4; ++r) {
                    float wv_ = acc[mt][r] * E[mt][r];
                    if (ovp && k == 0)              // exact t=0 init of chunk 0
                        wv_ = is_c0 ? ILds[mt * 16 + g * 4 + r] * E[mt][r] : wv_;
                    w[mt][r] = wv_;
                }
            float scale = 1.f;
            if (k == 7) {                           // per-pack surrogate rescale
                c = __uint_as_float(__builtin_amdgcn_ds_bpermute(s << 2, __float_as_uint(w[0][0])));
                c = fmaxf(c, 1e-37f);
                Ls += __log2f(c);
                scale = __builtin_amdgcn_rcpf(c);
            }
            // C-layout -> B-layout transpose (packed bf16), <=2-way banks
#pragma unroll
            for (int mt = 0; mt < 4; ++mt)
#pragma unroll
                for (int pr = 0; pr < 2; ++pr) {
                    float v0 = w[mt][2 * pr], v1 = w[mt][2 * pr + 1];
                    if (k == 7) { v0 *= scale; v1 *= scale; }
                    wsc[(2 * g + pr + 8 * mt) * WSTR + s] = pk_trunc(v0, v1);
                }
#pragma unroll
            for (int kf = 0; kf < 2; ++kf)
#pragma unroll
                for (int j = 0; j < 4; ++j)
                    Bf[kf].u[j] = wsc[(4 * g + j + 16 * kf) * WSTR + s];
        }
        if (p == BURNP - 1) {                       // mass baseline S0
            float sw = 0.f;
#pragma unroll
            for (int mt = 0; mt < 4; ++mt)
#pragma unroll
                for (int r = 0; r < 4; ++r) sw += w[mt][r];
            sw += __shfl_xor(sw, 16);
            sw += __shfl_xor(sw, 32);
            S0v = (chunk == 0) ? Ls : (Ls + __log2f(sw) - __log2f(c));
        }
        u = un;
    }

    float sw = 0.f;
#pragma unroll
    for (int mt = 0; mt < 4; ++mt)
#pragma unroll
        for (int r = 0; r < 4; ++r) sw += w[mt][r];
    sw += __shfl_xor(sw, 16);
    sw += __shfl_xor(sw, 32);
    float Lfin = Ls + __log2f(sw) - __log2f(c) - S0v;
    if (lane < 16)
        atomicAdd(out + seq, Lfin * 0.6931471805599453f);
}

extern "C" void kernel_launch(void* const* d_in, const int* in_sizes, int n_in,
                              void* d_out, int out_size, void* d_ws, size_t ws_size,
                              hipStream_t stream) {
    const float* x  = (const float*)d_in[0];   // [B,T,M] one-hot
    const float* I  = (const float*)d_in[1];   // [1,S]
    const float* A  = (const float*)d_in[2];   // [S,S]
    const float* Bm = (const float*)d_in[3];   // [M,S]
    float* out = (float*)d_out;                // [B,1]
    unsigned char* obs = (unsigned char*)d_ws; // B*T = 2 MB of uint8

    hipMemsetAsync(out, 0, (size_t)out_size * sizeof(float), stream);
    extract_obs<<<65536, 256, 0, stream>>>((const float4*)x, obs);
    hmm_mfma<<<(BATCH * 8) / WPB, WPB * 64, 0, stream>>>(obs, I, A, Bm, out);  // 512 blocks, 4096 waves
}

// Round 8
// 1340.551 us; speedup vs baseline: 1.0199x; 1.0199x over previous
//
#include <hip/hip_runtime.h>

// HMM forward (CgpHmmCell): B=512, T=4096, S=64, M=125.
// Round 8: ILP over TLP. Measured R6/R7 invariant: time ~ 0.71-0.75 ns per
// wave-step regardless of 1 vs 4 waves/SIMD => per-wave serial chain bound
// (~1730 cyc/step: MFMA -> E-mult -> pack -> LDS write -> LDS read -> MFMA).
// Fix: FOUR independent chunk-chains per wave (64 streams); while chain A
// waits on LDS, chains B/C/D issue. 1 wave/SIMD on purpose; no VGPR cap.
//  - All 4 chains share one wsc region (per-wave DS pipe is in-order:
//    B's writes process after A's reads) -> LDS 44.5 KB/block.
//  - wsc per-lane-row layout (stride 12 u32): 2x ds_write_b128 + 8x b32
//    reads, <=2-way banks everywhere; 14 DS ops/step (was 20).
//  - BmL unpadded (o is wave-uniform -> 4 distinct 16B addrs + broadcast).
//  - One atomicAdd per wave (its 64 streams all belong to one sequence).
// Algorithm identical to R7 (absmax 0): chunk=32 steps, burn=16; mass
// identity dL = S1 - S0 (surrogate scales cancel); chunk-0 exact I*E0
// override at its boundary.

#define BATCH 512
#define T 4096
#define S 64
#define M 125
#define CHUNKP 4   // packs per chunk (32 steps)
#define BURNP 2    // burn packs (16 steps)
#define NPACK 6
#define WPB 4
#define NQ 4       // chains per wave

typedef __attribute__((ext_vector_type(8))) short bf16x8;
typedef __attribute__((ext_vector_type(4))) float f32x4;
typedef __attribute__((ext_vector_type(4))) unsigned u32x4;

union BFU { unsigned u[4]; bf16x8 v; };

__device__ __forceinline__ unsigned pk_trunc(float a, float b) {
    return (__float_as_uint(b) & 0xFFFF0000u) | (__float_as_uint(a) >> 16);
}
__device__ __forceinline__ unsigned pk_rne(float a, float b) {
    unsigned ua = __float_as_uint(a); ua += 0x7FFFu + ((ua >> 16) & 1u);
    unsigned ub = __float_as_uint(b); ub += 0x7FFFu + ((ub >> 16) & 1u);
    return (ub & 0xFFFF0000u) | (ua >> 16);
}

// ---------------- Phase 1: one-hot -> byte index (HBM-floor) ----------------
__global__ __launch_bounds__(256) void extract_obs(const float4* __restrict__ x4,
                                                   unsigned char* __restrict__ obs) {
    const long long n4 = (long long)BATCH * T * M / 4;
    long long stride = (long long)gridDim.x * blockDim.x;
    for (long long i = (long long)blockIdx.x * blockDim.x + threadIdx.x; i < n4; i += stride) {
        float4 v = x4[i];
        if (v.x != 0.0f || v.y != 0.0f || v.z != 0.0f || v.w != 0.0f) {
            long long e = i * 4;
            if (v.x != 0.0f) { long long r = (e + 0) / M; obs[r] = (unsigned char)(e + 0 - r * M); }
            if (v.y != 0.0f) { long long r = (e + 1) / M; obs[r] = (unsigned char)(e + 1 - r * M); }
            if (v.z != 0.0f) { long long r = (e + 2) / M; obs[r] = (unsigned char)(e + 2 - r * M); }
            if (v.w != 0.0f) { long long r = (e + 3) / M; obs[r] = (unsigned char)(e + 3 - r * M); }
        }
    }
}

// ---------------- Phase 2: MFMA scan, 4 chains x 16 streams per wave --------
__global__ __launch_bounds__(256) void hmm_mfma(const unsigned char* __restrict__ obs,
                                                const float* __restrict__ Iv,
                                                const float* __restrict__ A,
                                                const float* __restrict__ Bm,
                                                float* __restrict__ out) {
    __shared__ __align__(16) float BmL[M * S];        // 32000 B, natural stride 64
    __shared__ __align__(16) float ILds[S];
    __shared__ u32x4 wscAll[WPB][64 * 3];             // 64 rows x 12 u32 per wave

    const int tid = threadIdx.x, wv = tid >> 6, lane = tid & 63;
    const int s = lane & 15, g = lane >> 4;

    for (int i = tid; i < M * S; i += WPB * 64) BmL[i] = Bm[i];
    if (tid < S) ILds[tid] = Iv[tid];
    __syncthreads();

    // Constant A^T fragments: Aop[m][k] = A[k][m]; lane (s,g): m=16mt+s, k=32kf+8g+j.
    BFU Af[4][2];
#pragma unroll
    for (int mt = 0; mt < 4; ++mt)
#pragma unroll
        for (int kf = 0; kf < 2; ++kf)
#pragma unroll
            for (int j2 = 0; j2 < 4; ++j2) {
                int k0 = kf * 32 + g * 8 + 2 * j2;
                Af[mt][kf].u[j2] = pk_rne(A[(size_t)k0 * S + mt * 16 + s],
                                          A[(size_t)(k0 + 1) * S + mt * 16 + s]);
            }

    const int W = blockIdx.x * WPB + wv;   // 0..1023
    const int seq = W >> 1, half = W & 1;  // 2 waves per sequence
    const unsigned long long* orow = (const unsigned long long*)(obs + (size_t)seq * T);
    unsigned* wsc = (unsigned*)wscAll[wv];

    // transpose addressing: write row = lane; read row = s + 16*G(g,a)
    const int wbase = lane * 12;
    int rbase[2];
#pragma unroll
    for (int a = 0; a < 2; ++a) {
        int t = 2 * g + a;
        rbase[a] = (s + 16 * (t & 3)) * 12 + (t >> 2) * 2;
    }

    int idx0[NQ];
    unsigned long long u[NQ], un[NQ];
    BFU Bf[NQ][2];
    float Ls[NQ], S0v[NQ], cc[NQ], swv[NQ];
#pragma unroll
    for (int q = 0; q < NQ; ++q) {
        int chunk = half * 64 + q * 16 + s;        // 0..127: this lane/chain's stream
        idx0[q] = chunk * CHUNKP - BURNP;
        u[q] = orow[idx0[q] < 0 ? 0 : idx0[q]];
        Ls[q] = 0.f; S0v[q] = 0.f; cc[q] = 1.f; swv[q] = 1.f;
#pragma unroll
        for (int kf = 0; kf < 2; ++kf)
#pragma unroll
            for (int j = 0; j < 4; ++j) Bf[q][kf].u[j] = 0x3F803F80u;  // 1.0 seed
    }

    for (int p = 0; p < NPACK; ++p) {
#pragma unroll
        for (int q = 0; q < NQ; ++q) {
            int in_ = idx0[q] + p + 1;
            in_ = in_ < 0 ? 0 : (in_ > T / 8 - 1 ? T / 8 - 1 : in_);
            un[q] = orow[in_];                      // prefetch next pack
        }
        const bool ovp = (half == 0) && (p == BURNP);
#pragma unroll
        for (int k = 0; k < 8; ++k) {
#pragma unroll
            for (int q = 0; q < NQ; ++q) {
                const int o = (int)((u[q] >> (8 * k)) & 255ull);
                const float* br = &BmL[o << 6];
                f32x4 E[4];
#pragma unroll
                for (int mt = 0; mt < 4; ++mt)
                    E[mt] = *(const f32x4*)&br[mt * 16 + g * 4];
                float w[4][4];
#pragma unroll
                for (int mt = 0; mt < 4; ++mt) {
                    f32x4 z = {0.f, 0.f, 0.f, 0.f};
                    z = __builtin_amdgcn_mfma_f32_16x16x32_bf16(Af[mt][0].v, Bf[q][0].v, z, 0, 0, 0);
                    z = __builtin_amdgcn_mfma_f32_16x16x32_bf16(Af[mt][1].v, Bf[q][1].v, z, 0, 0, 0);
#pragma unroll
                    for (int r = 0; r < 4; ++r) w[mt][r] = z[r] * E[mt][r];
                }
                if (ovp && k == 0 && q == 0) {      // exact t=0 init of chunk 0
                    const bool c0 = (s == 0);
#pragma unroll
                    for (int mt = 0; mt < 4; ++mt)
#pragma unroll
                        for (int r = 0; r < 4; ++r)
                            w[mt][r] = c0 ? ILds[mt * 16 + g * 4 + r] * E[mt][r] : w[mt][r];
                }
                float scale = 1.f;
                if (k == 7) {                       // per-pack surrogate rescale
                    float swl = 0.f;
#pragma unroll
                    for (int mt = 0; mt < 4; ++mt)
#pragma unroll
                        for (int r = 0; r < 4; ++r) swl += w[mt][r];
                    swl += __shfl_xor(swl, 16);
                    swl += __shfl_xor(swl, 32);
                    swv[q] = swl;                   // pre-scale mass (boundary/final)
                    float c = __uint_as_float(__builtin_amdgcn_ds_bpermute(s << 2, __float_as_uint(w[0][0])));
                    c = fmaxf(c, 1e-37f);
                    cc[q] = c;
                    Ls[q] += __log2f(c);
                    scale = __builtin_amdgcn_rcpf(c);
                }
                unsigned P[8];
#pragma unroll
                for (int mt = 0; mt < 4; ++mt)
#pragma unroll
                    for (int pr = 0; pr < 2; ++pr) {
                        float v0 = w[mt][2 * pr], v1 = w[mt][2 * pr + 1];
                        if (k == 7) { v0 *= scale; v1 *= scale; }
                        P[mt * 2 + pr] = pk_trunc(v0, v1);
                    }
                u32x4 w0 = {P[0], P[1], P[2], P[3]}, w1 = {P[4], P[5], P[6], P[7]};
                *(u32x4*)&wsc[wbase] = w0;          // 2x ds_write_b128, <=2-way banks
                *(u32x4*)&wsc[wbase + 4] = w1;
#pragma unroll
                for (int kf = 0; kf < 2; ++kf)
#pragma unroll
                    for (int j2 = 0; j2 < 4; ++j2)
                        Bf[q][kf].u[j2] = wsc[rbase[j2 >> 1] + 4 * kf + (j2 & 1)];
            }
        }
        if (p == BURNP - 1) {                       // mass baseline S0 per chain
#pragma unroll
            for (int q = 0; q < NQ; ++q) {
                const bool ch0 = (half == 0) && (q == 0) && (s == 0);
                S0v[q] = ch0 ? Ls[q] : (Ls[q] + __log2f(swv[q]) - __log2f(cc[q]));
            }
        }
#pragma unroll
        for (int q = 0; q < NQ; ++q) u[q] = un[q];
    }

    float tot = 0.f;
#pragma unroll
    for (int q = 0; q < NQ; ++q)
        tot += Ls[q] + __log2f(swv[q]) - __log2f(cc[q]) - S0v[q];
    // sum over the 16 streams (s-dim); g-lanes hold duplicates
    tot += __shfl_xor(tot, 1);
    tot += __shfl_xor(tot, 2);
    tot += __shfl_xor(tot, 4);
    tot += __shfl_xor(tot, 8);
    if (lane == 0)
        atomicAdd(out + seq, tot * 0.6931471805599453f);
}

extern "C" void kernel_launch(void* const* d_in, const int* in_sizes, int n_in,
                              void* d_out, int out_size, void* d_ws, size_t ws_size,
                              hipStream_t stream) {
    const float* x  = (const float*)d_in[0];   // [B,T,M] one-hot
    const float* I  = (const float*)d_in[1];   // [1,S]
    const float* A  = (const float*)d_in[2];   // [S,S]
    const float* Bm = (const float*)d_in[3];   // [M,S]
    float* out = (float*)d_out;                // [B,1]
    unsigned char* obs = (unsigned char*)d_ws; // B*T = 2 MB of uint8

    hipMemsetAsync(out, 0, (size_t)out_size * sizeof(float), stream);
    extract_obs<<<65536, 256, 0, stream>>>((const float4*)x, obs);
    hmm_mfma<<<256, WPB * 64, 0, stream>>>(obs, I, A, Bm, out);  // 1024 waves, 1 block/CU
}